// Round 12
// baseline (276.825 us; speedup 1.0000x reference)
//
#include <hip/hip_runtime.h>
#include <hip/hip_bf16.h>

#define N_NODES 50000
#define N_EDGES 800000
#define F_IN    128
#define F_HID   128
#define F_OUT   40
#define N_TILES (N_NODES / 16)                // 3125 (exact)

#define NBIN      98                          // bins of 512 nodes (dst >> 9)
#define BIN_SHIFT 9
#define EPB       1024                        // edges per bin block
#define CAP       32                          // LDS slots per bin
#define GBIN_CAP  9216                        // global slots per bin

#define CVT_BLOCKS ((F_IN * F_HID + 48 * F_HID) / 256)   // 88
#define BIN_BLOCKS ((N_EDGES + EPB - 1) / EPB)           // 782
#define G1_BLOCKS  ((N_TILES + 3) / 4)                   // 782
#define AGG1_NB    (N_NODES / 4)                         // 12500 blocks/pass (4 nodes/block)

typedef __attribute__((ext_vector_type(8))) short bf16x8;   // 8 bf16 = 4 VGPRs
typedef __attribute__((ext_vector_type(4))) float f32x4;

__device__ __forceinline__ float2 unpack_bf2(unsigned u) {
    float2 r;
    r.x = __uint_as_float(u << 16);
    r.y = __uint_as_float(u & 0xffff0000u);
    return r;
}
__device__ __forceinline__ unsigned pack_bf2(float x, float y) {
    union { unsigned u; __hip_bfloat16 h[2]; } cv;
    cv.h[0] = __float2bfloat16(x);
    cv.h[1] = __float2bfloat16(y);
    return cv.u;
}
__device__ __forceinline__ short bfraw(float v) {
    __hip_bfloat16 h = __float2bfloat16(v);
    return *(short*)&h;
}
__device__ __forceinline__ float bf16u_to_f32(unsigned short us) {
    return __uint_as_float(((unsigned)us) << 16);
}
__device__ __forceinline__ unsigned f32_to_h16(float v) {
    _Float16 h = (_Float16)v;
    return (unsigned)*(unsigned short*)&h;
}
__device__ __forceinline__ float h16_to_f32(unsigned bits) {
    unsigned short us = (unsigned short)bits;
    _Float16 h = *(_Float16*)&us;
    return (float)h;
}

__device__ __forceinline__ int ld_src(const unsigned int* w, int is64, int e) {
    return is64 ? (int)w[2 * e] : (int)w[e];
}
__device__ __forceinline__ int ld_dst(const unsigned int* w, int is64, int e) {
    return is64 ? (int)w[2 * (N_EDGES + e)] : (int)w[N_EDGES + e];
}

// ---- 1. init: blocks 0..87 convert W1/W2 to transposed bf16; block 88 sniffs
//         index width and zeroes gcnt.
__global__ void k_init(const unsigned int* __restrict__ ew,
                       const float* __restrict__ W1, const float* __restrict__ W2,
                       __hip_bfloat16* __restrict__ w1t, __hip_bfloat16* __restrict__ w2t,
                       int* __restrict__ flag, int* __restrict__ gcnt) {
    int b = blockIdx.x, t = threadIdx.x;
    if (b < CVT_BLOCKS) {
        int idx = b * 256 + t;
        if (idx < F_IN * F_HID) {
            int n = idx >> 7, k = idx & 127;
            w1t[idx] = __float2bfloat16(W1[k * F_HID + n]);
        } else {
            int j = idx - F_IN * F_HID;          // 0 .. 6143
            int n = j >> 7, k = j & 127;
            w2t[j] = __float2bfloat16(n < F_OUT ? W2[k * F_OUT + n] : 0.f);
        }
        return;
    }
    __shared__ int nz;
    if (t == 0) nz = 0;
    __syncthreads();
    int local = 0;
    for (int i = t; i < 4096; i += 256)
        if (ew[2 * i + 1] != 0u) local = 1;
    if (local) atomicOr(&nz, 1);
    if (t < NBIN) gcnt[t] = 0;
    __syncthreads();
    if (t == 0) flag[0] = (nz == 0) ? 1 : 0;     // 1 => int64 layout
}

// ---- 2. merged: blocks [0,782) bin edges; blocks [782,1564) MFMA gemm1.
//         h1b written SLICE-MAJOR: h1b[pass][node][32], pass = feat>>5.
__global__ void k_bing1(const unsigned int* __restrict__ ew, const int* __restrict__ flag,
                        int* __restrict__ gcnt, unsigned* __restrict__ gbin,
                        const float* __restrict__ x, const __hip_bfloat16* __restrict__ w1t,
                        __hip_bfloat16* __restrict__ h1b) {
    __shared__ unsigned buf[NBIN][CAP];        // 12.5 KB (unused by gemm blocks)
    __shared__ int cnt[NBIN];
    __shared__ int base[NBIN];
    int t = threadIdx.x;
    if (blockIdx.x < BIN_BLOCKS) {
        for (int i = t; i < NBIN; i += 256) cnt[i] = 0;
        __syncthreads();
        int is64 = flag[0];
        int e0 = blockIdx.x * EPB;
        int n = min(EPB, N_EDGES - e0);
        for (int i = t; i < n; i += 256) {
            int e = e0 + i;
            int s = ld_src(ew, is64, e), d = ld_dst(ew, is64, e);
            unsigned rec = (unsigned)s | ((unsigned)d << 16);
            int b = d >> BIN_SHIFT;
            int c = atomicAdd(&cnt[b], 1);
            if (c < CAP) buf[b][c] = rec;
            else {
                int g = atomicAdd(&gcnt[b], 1);
                gbin[(size_t)b * GBIN_CAP + g] = rec;
            }
        }
        __syncthreads();
        if (t < NBIN) {
            int m = min(cnt[t], CAP);
            base[t] = atomicAdd(&gcnt[t], m);
            cnt[t] = m;
        }
        __syncthreads();
        int wave = t >> 6, lane = t & 63;
        for (int b = wave; b < NBIN; b += 4) {
            int m = cnt[b], bs = base[b];
            for (int i = lane; i < m; i += 64)
                gbin[(size_t)b * GBIN_CAP + bs + i] = buf[b][i];
        }
        return;
    }
    // ---- gemm1 part
    int wave = t >> 6, lane = t & 63;
    int tile = (blockIdx.x - BIN_BLOCKS) * 4 + wave;
    if (tile >= N_TILES) return;
    int node0 = tile * 16;
    int m = lane & 15, q = lane >> 4;
    bf16x8 A[4];
    const float* arow = x + (size_t)(node0 + m) * F_IN + q * 8;
#pragma unroll
    for (int kt = 0; kt < 4; kt++) {
        float4 f0 = *(const float4*)(arow + kt * 32);
        float4 f1 = *(const float4*)(arow + kt * 32 + 4);
        bf16x8 a;
        a[0] = bfraw(f0.x); a[1] = bfraw(f0.y); a[2] = bfraw(f0.z); a[3] = bfraw(f0.w);
        a[4] = bfraw(f1.x); a[5] = bfraw(f1.y); a[6] = bfraw(f1.z); a[7] = bfraw(f1.w);
        A[kt] = a;
    }
#pragma unroll
    for (int c = 0; c < 8; c++) {
        f32x4 acc = {0.f, 0.f, 0.f, 0.f};
        const __hip_bfloat16* brow = w1t + (size_t)(c * 16 + m) * F_IN + q * 8;
#pragma unroll
        for (int kt = 0; kt < 4; kt++) {
            bf16x8 B = *(const bf16x8*)(brow + kt * 32);
            acc = __builtin_amdgcn_mfma_f32_16x16x32_bf16(A[kt], B, acc, 0, 0, 0);
        }
        int feat = c * 16 + m;
        int pass = feat >> 5, fs = feat & 31;
#pragma unroll
        for (int r = 0; r < 4; r++)
            h1b[(size_t)pass * N_NODES * 32 + (size_t)(node0 + q * 4 + r) * 32 + fs] =
                __float2bfloat16(acc[r]);
    }
}

// ---- 3. passB1: per-bin node histogram + scan -> rowptr, dinv (one block per bin)
__global__ void k_passB1(const int* __restrict__ gcnt, const unsigned* __restrict__ gbin,
                         int* __restrict__ rowptr, float* __restrict__ dinv) {
    __shared__ int c[512];
    __shared__ int s2[256];
    __shared__ int gall[NBIN];
    __shared__ int bbase;
    int t = threadIdx.x;
    int b = blockIdx.x;
    c[t] = 0; c[t + 256] = 0;
    if (t < NBIN) gall[t] = gcnt[t];
    __syncthreads();
    if (t == 0) {
        int s = 0;
        for (int i = 0; i < b; i++) s += gall[i];
        bbase = s;
    }
    int n = gall[b];
    const unsigned* rec = gbin + (size_t)b * GBIN_CAP;
    int base512 = b << BIN_SHIFT;
    for (int i = t; i < n; i += 256)
        atomicAdd(&c[(int)(rec[i] >> 16) - base512], 1);
    __syncthreads();
    int a0 = c[2 * t], a1 = c[2 * t + 1];
    s2[t] = a0 + a1;
    __syncthreads();
    for (int off = 1; off < 256; off <<= 1) {
        int u = (t >= off) ? s2[t - off] : 0;
        __syncthreads();
        s2[t] += u;
        __syncthreads();
    }
    int ebase = bbase + s2[t] - a0 - a1;
    int i0 = base512 + 2 * t, i1 = i0 + 1;
    if (i0 < N_NODES) { rowptr[i0] = ebase;      dinv[i0] = rsqrtf((float)a0 + 1.f); }
    if (i1 < N_NODES) { rowptr[i1] = ebase + a0; dinv[i1] = rsqrtf((float)a1 + 1.f); }
    if (b == 0 && t == 0) rowptr[N_NODES] = N_EDGES;
}

// ---- 4. passB2: scatter bin records to final CSR slots (block-local dense window)
__global__ void k_passB2(const int* __restrict__ gcnt, const unsigned* __restrict__ gbin,
                         const int* __restrict__ rowptr, const float* __restrict__ dinv,
                         unsigned* __restrict__ srcw) {
    __shared__ int pos[512];
    __shared__ float dloc[512];
    int t = threadIdx.x;
    int b = blockIdx.x;
    int base512 = b << BIN_SHIFT;
#pragma unroll
    for (int k = 0; k < 2; k++) {
        int j = t + k * 256;
        int i = base512 + j;
        pos[j]  = (i < N_NODES) ? rowptr[i] : 0;
        dloc[j] = (i < N_NODES) ? dinv[i] : 0.f;
    }
    __syncthreads();
    int n = gcnt[b];
    const unsigned* rec = gbin + (size_t)b * GBIN_CAP;
    for (int i = t; i < n; i += 256) {
        unsigned r = rec[i];
        int s  = (int)(r & 0xFFFFu);
        int dl = (int)(r >> 16) - base512;
        int slot = atomicAdd(&pos[dl], 1);
        float norm = dinv[s] * dloc[dl];
        srcw[slot] = (unsigned)s | (f32_to_h16(norm) << 16);
    }
}

// ---- 5. feature-sliced layer-1 aggregate + self-loop + bias + relu.
//         pass = blockIdx.x / AGG1_NB selects a 3.2 MB h1b slice (fits per-XCD L2).
//         One wave per node per pass; 4 edges x 16 lanes; cross-sub shfl reduce.
__global__ void k_agg1s(const int* __restrict__ rowptr, const unsigned* __restrict__ srcw,
                        const float* __restrict__ dinv, const __hip_bfloat16* __restrict__ h1b,
                        const float* __restrict__ b1, __hip_bfloat16* __restrict__ h1rb) {
    int wave = threadIdx.x >> 6, lane = threadIdx.x & 63;
    int pass = blockIdx.x / AGG1_NB;            // 0..3 (pass-major => near-lockstep)
    int node = (blockIdx.x % AGG1_NB) * 4 + wave;
    int sub = lane >> 4, f2 = lane & 15;
    const unsigned* slice = (const unsigned*)h1b + (size_t)pass * N_NODES * 16;
    int beg = rowptr[node], end = rowptr[node + 1];
    float accx = 0.f, accy = 0.f;
    for (int e = beg; e < end; e += 8) {        // 2x unrolled, 4 edges per sub-step
        int e0 = e + sub, e1 = e + 4 + sub;
        bool ok0 = e0 < end, ok1 = e1 < end;
        unsigned p0 = ok0 ? srcw[e0] : 0u;
        unsigned p1 = ok1 ? srcw[e1] : 0u;
        float2 v0 = {0.f, 0.f}, v1 = {0.f, 0.f};
        if (ok0) v0 = unpack_bf2(slice[(size_t)(p0 & 0xFFFFu) * 16 + f2]);
        if (ok1) v1 = unpack_bf2(slice[(size_t)(p1 & 0xFFFFu) * 16 + f2]);
        float w0 = ok0 ? h16_to_f32(p0 >> 16) : 0.f;
        float w1 = ok1 ? h16_to_f32(p1 >> 16) : 0.f;
        accx += v0.x * w0 + v1.x * w1;
        accy += v0.y * w0 + v1.y * w1;
    }
    // reduce across the 4 sub-groups (lanes with equal f2)
    accx += __shfl_xor(accx, 16); accy += __shfl_xor(accy, 16);
    accx += __shfl_xor(accx, 32); accy += __shfl_xor(accy, 32);
    if (sub == 0) {
        float di = dinv[node];
        float2 self = unpack_bf2(slice[(size_t)node * 16 + f2]);
        float2 bb = ((const float2*)b1)[pass * 16 + f2];
        float ax = fmaxf(accx + self.x * di * di + bb.x, 0.f);
        float ay = fmaxf(accy + self.y * di * di + bb.y, 0.f);
        ((unsigned*)h1rb)[(size_t)node * 64 + pass * 16 + f2] = pack_bf2(ax, ay);
    }
}

// ---- 6. h2 = h1r @ W2 via MFMA (N padded 40->48). h2 out BF16.
__global__ void k_gemm2m(const __hip_bfloat16* __restrict__ h1rb,
                         const __hip_bfloat16* __restrict__ w2t,
                         __hip_bfloat16* __restrict__ h2b) {
    int wave = threadIdx.x >> 6, lane = threadIdx.x & 63;
    int tile = blockIdx.x * 4 + wave;
    if (tile >= N_TILES) return;
    int node0 = tile * 16;
    int m = lane & 15, q = lane >> 4;
    bf16x8 A[4];
    const __hip_bfloat16* arow = h1rb + (size_t)(node0 + m) * F_HID + q * 8;
#pragma unroll
    for (int kt = 0; kt < 4; kt++)
        A[kt] = *(const bf16x8*)(arow + kt * 32);
#pragma unroll
    for (int c = 0; c < 3; c++) {
        f32x4 acc = {0.f, 0.f, 0.f, 0.f};
        const __hip_bfloat16* brow = w2t + (size_t)(c * 16 + m) * F_HID + q * 8;
#pragma unroll
        for (int kt = 0; kt < 4; kt++) {
            bf16x8 B = *(const bf16x8*)(brow + kt * 32);
            acc = __builtin_amdgcn_mfma_f32_16x16x32_bf16(A[kt], B, acc, 0, 0, 0);
        }
        int col = c * 16 + m;
        if (col < F_OUT) {
#pragma unroll
            for (int r = 0; r < 4; r++)
                h2b[(size_t)(node0 + q * 4 + r) * F_OUT + col] = __float2bfloat16(acc[r]);
        }
    }
}

// ---- 7. fused layer-2 aggregate + self-loop + bias + log_softmax. bf16 h2 gather.
__global__ void k_agg2f(const int* __restrict__ rowptr, const unsigned* __restrict__ srcw,
                        const float* __restrict__ dinv,
                        const unsigned short* __restrict__ h2b,
                        const float* __restrict__ b2, float* __restrict__ out) {
    int wave = threadIdx.x >> 6, lane = threadIdx.x & 63;
    int node = blockIdx.x * 4 + wave;
    float di = dinv[node];
    int beg = rowptr[node], end = rowptr[node + 1];
    int l = (lane < F_OUT) ? lane : 0;
    float acc = bf16u_to_f32(h2b[(size_t)node * F_OUT + l]) * di * di;
    int e = beg;
    for (; e + 3 < end; e += 4) {
        unsigned p0 = srcw[e], p1 = srcw[e + 1], p2 = srcw[e + 2], p3 = srcw[e + 3];
        float v0 = bf16u_to_f32(h2b[(size_t)(p0 & 0xFFFF) * F_OUT + l]);
        float v1 = bf16u_to_f32(h2b[(size_t)(p1 & 0xFFFF) * F_OUT + l]);
        float v2 = bf16u_to_f32(h2b[(size_t)(p2 & 0xFFFF) * F_OUT + l]);
        float v3 = bf16u_to_f32(h2b[(size_t)(p3 & 0xFFFF) * F_OUT + l]);
        acc += v0 * h16_to_f32(p0 >> 16) + v1 * h16_to_f32(p1 >> 16)
             + v2 * h16_to_f32(p2 >> 16) + v3 * h16_to_f32(p3 >> 16);
    }
    for (; e < end; e++) {
        unsigned p = srcw[e];
        acc += bf16u_to_f32(h2b[(size_t)(p & 0xFFFF) * F_OUT + l]) * h16_to_f32(p >> 16);
    }
    float v = (lane < F_OUT) ? acc + b2[lane] : -INFINITY;
    float m = v;
    for (int off = 32; off; off >>= 1) m = fmaxf(m, __shfl_xor(m, off));
    float ex = (lane < F_OUT) ? __expf(v - m) : 0.f;
    float ssum = ex;
    for (int off = 32; off; off >>= 1) ssum += __shfl_xor(ssum, off);
    float ls = __logf(ssum);
    if (lane < F_OUT)
        out[(size_t)node * F_OUT + lane] = v - m - ls;
}

extern "C" void kernel_launch(void* const* d_in, const int* in_sizes, int n_in,
                              void* d_out, int out_size, void* d_ws, size_t ws_size,
                              hipStream_t stream) {
    const float* x  = (const float*)d_in[0];
    const float* W1 = (const float*)d_in[1];
    const float* b1 = (const float*)d_in[2];
    const float* W2 = (const float*)d_in[3];
    const float* b2 = (const float*)d_in[4];
    const unsigned int* ew = (const unsigned int*)d_in[5];
    float* out = (float*)d_out;

    // workspace (~37 MB)
    char* ws = (char*)d_ws;
    int*   flag     = (int*)ws;   ws += 256;
    int*   gcnt     = (int*)ws;   ws += 512;
    float* dinv     = (float*)ws; ws += ((N_NODES * 4 + 255) / 256) * 256;
    int*   rowptr   = (int*)ws;   ws += (((N_NODES + 1) * 4 + 255) / 256) * 256;
    unsigned* gbin  = (unsigned*)ws; ws += (size_t)NBIN * GBIN_CAP * 4;   // 3.6 MB
    unsigned* srcw  = (unsigned*)ws; ws += (size_t)N_EDGES * 4;           // 3.2 MB
    __hip_bfloat16* w1t  = (__hip_bfloat16*)ws; ws += F_IN * F_HID * 2;
    __hip_bfloat16* w2t  = (__hip_bfloat16*)ws; ws += 48 * F_HID * 2;
    __hip_bfloat16* h1b  = (__hip_bfloat16*)ws; ws += (size_t)N_NODES * F_HID * 2;  // slice-major [4][N][32]
    __hip_bfloat16* h1rb = (__hip_bfloat16*)ws; ws += (size_t)N_NODES * F_HID * 2;  // row-major
    __hip_bfloat16* h2b  = (__hip_bfloat16*)ws; ws += (size_t)N_NODES * F_OUT * 2;

    k_init   <<<CVT_BLOCKS + 1, 256, 0, stream>>>(ew, W1, W2, w1t, w2t, flag, gcnt);
    k_bing1  <<<BIN_BLOCKS + G1_BLOCKS, 256, 0, stream>>>(ew, flag, gcnt, gbin, x, w1t, h1b);
    k_passB1 <<<NBIN, 256, 0, stream>>>(gcnt, gbin, rowptr, dinv);
    k_passB2 <<<NBIN, 256, 0, stream>>>(gcnt, gbin, rowptr, dinv, srcw);
    k_agg1s  <<<4 * AGG1_NB, 256, 0, stream>>>(rowptr, srcw, dinv, h1b, b1, h1rb);
    k_gemm2m <<<(N_TILES + 3) / 4, 256, 0, stream>>>(h1rb, w2t, h2b);
    k_agg2f  <<<N_NODES / 4, 256, 0, stream>>>(rowptr, srcw, dinv,
                                               (const unsigned short*)h2b, b2, out);
}

// Round 13
// 224.704 us; speedup vs baseline: 1.2320x; 1.2320x over previous
//
#include <hip/hip_runtime.h>
#include <hip/hip_bf16.h>

#define N_NODES 50000
#define N_EDGES 800000
#define F_IN    128
#define F_HID   128
#define F_OUT   40
#define N_TILES (N_NODES / 16)                // 3125 (exact)

#define NBIN      98                          // bins of 512 nodes (dst >> 9)
#define BIN_SHIFT 9
#define EPB       1024                        // edges per bin block
#define CAP       32                          // LDS slots per bin
#define GBIN_CAP  9216                        // global slots per bin

#define CVT_BLOCKS ((F_IN * F_HID + 48 * F_HID) / 256)   // 88
#define BIN_BLOCKS ((N_EDGES + EPB - 1) / EPB)           // 782
#define G1_BLOCKS  ((N_TILES + 3) / 4)                   // 782

typedef __attribute__((ext_vector_type(8))) short bf16x8;   // 8 bf16 = 4 VGPRs
typedef __attribute__((ext_vector_type(4))) float f32x4;

__device__ __forceinline__ float2 unpack_bf2(unsigned u) {
    float2 r;
    r.x = __uint_as_float(u << 16);
    r.y = __uint_as_float(u & 0xffff0000u);
    return r;
}
__device__ __forceinline__ unsigned pack_bf2(float x, float y) {
    union { unsigned u; __hip_bfloat16 h[2]; } cv;
    cv.h[0] = __float2bfloat16(x);
    cv.h[1] = __float2bfloat16(y);
    return cv.u;
}
__device__ __forceinline__ short bfraw(float v) {
    __hip_bfloat16 h = __float2bfloat16(v);
    return *(short*)&h;
}
__device__ __forceinline__ float bf16u_to_f32(unsigned short us) {
    return __uint_as_float(((unsigned)us) << 16);
}
__device__ __forceinline__ unsigned f32_to_h16(float v) {
    _Float16 h = (_Float16)v;
    return (unsigned)*(unsigned short*)&h;
}
__device__ __forceinline__ float h16_to_f32(unsigned bits) {
    unsigned short us = (unsigned short)bits;
    _Float16 h = *(_Float16*)&us;
    return (float)h;
}

__device__ __forceinline__ int ld_src(const unsigned int* w, int is64, int e) {
    return is64 ? (int)w[2 * e] : (int)w[e];
}
__device__ __forceinline__ int ld_dst(const unsigned int* w, int is64, int e) {
    return is64 ? (int)w[2 * (N_EDGES + e)] : (int)w[N_EDGES + e];
}

// ---- 1. init: blocks 0..87 convert W1/W2 to transposed bf16; block 88 sniffs
//         index width and zeroes gcnt.
__global__ void k_init(const unsigned int* __restrict__ ew,
                       const float* __restrict__ W1, const float* __restrict__ W2,
                       __hip_bfloat16* __restrict__ w1t, __hip_bfloat16* __restrict__ w2t,
                       int* __restrict__ flag, int* __restrict__ gcnt) {
    int b = blockIdx.x, t = threadIdx.x;
    if (b < CVT_BLOCKS) {
        int idx = b * 256 + t;
        if (idx < F_IN * F_HID) {
            int n = idx >> 7, k = idx & 127;
            w1t[idx] = __float2bfloat16(W1[k * F_HID + n]);
        } else {
            int j = idx - F_IN * F_HID;          // 0 .. 6143
            int n = j >> 7, k = j & 127;
            w2t[j] = __float2bfloat16(n < F_OUT ? W2[k * F_OUT + n] : 0.f);
        }
        return;
    }
    __shared__ int nz;
    if (t == 0) nz = 0;
    __syncthreads();
    int local = 0;
    for (int i = t; i < 4096; i += 256)
        if (ew[2 * i + 1] != 0u) local = 1;
    if (local) atomicOr(&nz, 1);
    if (t < NBIN) gcnt[t] = 0;
    __syncthreads();
    if (t == 0) flag[0] = (nz == 0) ? 1 : 0;     // 1 => int64 layout
}

// ---- 2. merged: blocks [0,782) bin edges; blocks [782,1564) MFMA gemm1 (row-major h1b).
__global__ void k_bing1(const unsigned int* __restrict__ ew, const int* __restrict__ flag,
                        int* __restrict__ gcnt, unsigned* __restrict__ gbin,
                        const float* __restrict__ x, const __hip_bfloat16* __restrict__ w1t,
                        __hip_bfloat16* __restrict__ h1b) {
    __shared__ unsigned buf[NBIN][CAP];        // 12.5 KB (unused by gemm blocks)
    __shared__ int cnt[NBIN];
    __shared__ int base[NBIN];
    int t = threadIdx.x;
    if (blockIdx.x < BIN_BLOCKS) {
        for (int i = t; i < NBIN; i += 256) cnt[i] = 0;
        __syncthreads();
        int is64 = flag[0];
        int e0 = blockIdx.x * EPB;
        int n = min(EPB, N_EDGES - e0);
        for (int i = t; i < n; i += 256) {
            int e = e0 + i;
            int s = ld_src(ew, is64, e), d = ld_dst(ew, is64, e);
            unsigned rec = (unsigned)s | ((unsigned)d << 16);
            int b = d >> BIN_SHIFT;
            int c = atomicAdd(&cnt[b], 1);
            if (c < CAP) buf[b][c] = rec;
            else {
                int g = atomicAdd(&gcnt[b], 1);
                gbin[(size_t)b * GBIN_CAP + g] = rec;
            }
        }
        __syncthreads();
        if (t < NBIN) {
            int m = min(cnt[t], CAP);
            base[t] = atomicAdd(&gcnt[t], m);
            cnt[t] = m;
        }
        __syncthreads();
        int wave = t >> 6, lane = t & 63;
        for (int b = wave; b < NBIN; b += 4) {
            int m = cnt[b], bs = base[b];
            for (int i = lane; i < m; i += 64)
                gbin[(size_t)b * GBIN_CAP + bs + i] = buf[b][i];
        }
        return;
    }
    // ---- gemm1 part
    int wave = t >> 6, lane = t & 63;
    int tile = (blockIdx.x - BIN_BLOCKS) * 4 + wave;
    if (tile >= N_TILES) return;
    int node0 = tile * 16;
    int m = lane & 15, q = lane >> 4;
    bf16x8 A[4];
    const float* arow = x + (size_t)(node0 + m) * F_IN + q * 8;
#pragma unroll
    for (int kt = 0; kt < 4; kt++) {
        float4 f0 = *(const float4*)(arow + kt * 32);
        float4 f1 = *(const float4*)(arow + kt * 32 + 4);
        bf16x8 a;
        a[0] = bfraw(f0.x); a[1] = bfraw(f0.y); a[2] = bfraw(f0.z); a[3] = bfraw(f0.w);
        a[4] = bfraw(f1.x); a[5] = bfraw(f1.y); a[6] = bfraw(f1.z); a[7] = bfraw(f1.w);
        A[kt] = a;
    }
#pragma unroll
    for (int c = 0; c < 8; c++) {
        f32x4 acc = {0.f, 0.f, 0.f, 0.f};
        const __hip_bfloat16* brow = w1t + (size_t)(c * 16 + m) * F_IN + q * 8;
#pragma unroll
        for (int kt = 0; kt < 4; kt++) {
            bf16x8 B = *(const bf16x8*)(brow + kt * 32);
            acc = __builtin_amdgcn_mfma_f32_16x16x32_bf16(A[kt], B, acc, 0, 0, 0);
        }
#pragma unroll
        for (int r = 0; r < 4; r++)
            h1b[(size_t)(node0 + q * 4 + r) * F_HID + c * 16 + m] = __float2bfloat16(acc[r]);
    }
}

// ---- 3. passB1: per-bin node histogram + scan -> rowptr, dinv (one block per bin)
__global__ void k_passB1(const int* __restrict__ gcnt, const unsigned* __restrict__ gbin,
                         int* __restrict__ rowptr, float* __restrict__ dinv) {
    __shared__ int c[512];
    __shared__ int s2[256];
    __shared__ int gall[NBIN];
    __shared__ int bbase;
    int t = threadIdx.x;
    int b = blockIdx.x;
    c[t] = 0; c[t + 256] = 0;
    if (t < NBIN) gall[t] = gcnt[t];
    __syncthreads();
    if (t == 0) {
        int s = 0;
        for (int i = 0; i < b; i++) s += gall[i];
        bbase = s;
    }
    int n = gall[b];
    const unsigned* rec = gbin + (size_t)b * GBIN_CAP;
    int base512 = b << BIN_SHIFT;
    for (int i = t; i < n; i += 256)
        atomicAdd(&c[(int)(rec[i] >> 16) - base512], 1);
    __syncthreads();
    int a0 = c[2 * t], a1 = c[2 * t + 1];
    s2[t] = a0 + a1;
    __syncthreads();
    for (int off = 1; off < 256; off <<= 1) {
        int u = (t >= off) ? s2[t - off] : 0;
        __syncthreads();
        s2[t] += u;
        __syncthreads();
    }
    int ebase = bbase + s2[t] - a0 - a1;
    int i0 = base512 + 2 * t, i1 = i0 + 1;
    if (i0 < N_NODES) { rowptr[i0] = ebase;      dinv[i0] = rsqrtf((float)a0 + 1.f); }
    if (i1 < N_NODES) { rowptr[i1] = ebase + a0; dinv[i1] = rsqrtf((float)a1 + 1.f); }
    if (b == 0 && t == 0) rowptr[N_NODES] = N_EDGES;
}

// ---- 4. passB2: scatter bin records to final CSR slots (block-local dense window)
__global__ void k_passB2(const int* __restrict__ gcnt, const unsigned* __restrict__ gbin,
                         const int* __restrict__ rowptr, const float* __restrict__ dinv,
                         unsigned* __restrict__ srcw) {
    __shared__ int pos[512];
    __shared__ float dloc[512];
    int t = threadIdx.x;
    int b = blockIdx.x;
    int base512 = b << BIN_SHIFT;
#pragma unroll
    for (int k = 0; k < 2; k++) {
        int j = t + k * 256;
        int i = base512 + j;
        pos[j]  = (i < N_NODES) ? rowptr[i] : 0;
        dloc[j] = (i < N_NODES) ? dinv[i] : 0.f;
    }
    __syncthreads();
    int n = gcnt[b];
    const unsigned* rec = gbin + (size_t)b * GBIN_CAP;
    for (int i = t; i < n; i += 256) {
        unsigned r = rec[i];
        int s  = (int)(r & 0xFFFFu);
        int dl = (int)(r >> 16) - base512;
        int slot = atomicAdd(&pos[dl], 1);
        float norm = dinv[s] * dloc[dl];
        srcw[slot] = (unsigned)s | (f32_to_h16(norm) << 16);
    }
}

// ---- 5. fused layer-1 aggregate + self-loop + bias + relu. One wave/node, unroll x4.
__global__ void k_agg1f(const int* __restrict__ rowptr, const unsigned* __restrict__ srcw,
                        const float* __restrict__ dinv, const __hip_bfloat16* __restrict__ h1b,
                        const float* __restrict__ b1, __hip_bfloat16* __restrict__ h1rb) {
    int wave = threadIdx.x >> 6, lane = threadIdx.x & 63;
    int node = blockIdx.x * 4 + wave;
    float di = dinv[node];
    int beg = rowptr[node], end = rowptr[node + 1];
    const unsigned* h1u = (const unsigned*)h1b;
    float2 acc = unpack_bf2(h1u[(size_t)node * 64 + lane]);
    float w0 = di * di;
    acc.x *= w0; acc.y *= w0;
    int e = beg;
    for (; e + 3 < end; e += 4) {
        unsigned p0 = srcw[e], p1 = srcw[e + 1], p2 = srcw[e + 2], p3 = srcw[e + 3];
        unsigned u0 = h1u[(size_t)(p0 & 0xFFFF) * 64 + lane];
        unsigned u1 = h1u[(size_t)(p1 & 0xFFFF) * 64 + lane];
        unsigned u2 = h1u[(size_t)(p2 & 0xFFFF) * 64 + lane];
        unsigned u3 = h1u[(size_t)(p3 & 0xFFFF) * 64 + lane];
        float w0e = h16_to_f32(p0 >> 16);
        float w1e = h16_to_f32(p1 >> 16);
        float w2e = h16_to_f32(p2 >> 16);
        float w3e = h16_to_f32(p3 >> 16);
        float2 v0 = unpack_bf2(u0), v1 = unpack_bf2(u1), v2 = unpack_bf2(u2), v3 = unpack_bf2(u3);
        acc.x += v0.x * w0e + v1.x * w1e + v2.x * w2e + v3.x * w3e;
        acc.y += v0.y * w0e + v1.y * w1e + v2.y * w2e + v3.y * w3e;
    }
    for (; e < end; e++) {
        unsigned p = srcw[e];
        float w = h16_to_f32(p >> 16);
        float2 v = unpack_bf2(h1u[(size_t)(p & 0xFFFF) * 64 + lane]);
        acc.x += v.x * w;
        acc.y += v.y * w;
    }
    float2 bb = ((const float2*)b1)[lane];
    acc.x = fmaxf(acc.x + bb.x, 0.f);
    acc.y = fmaxf(acc.y + bb.y, 0.f);
    ((unsigned*)h1rb)[(size_t)node * 64 + lane] = pack_bf2(acc.x, acc.y);
}

// ---- 6. h2 = h1r @ W2 via MFMA (N padded 40->48). h2 out BF16.
__global__ void k_gemm2m(const __hip_bfloat16* __restrict__ h1rb,
                         const __hip_bfloat16* __restrict__ w2t,
                         __hip_bfloat16* __restrict__ h2b) {
    int wave = threadIdx.x >> 6, lane = threadIdx.x & 63;
    int tile = blockIdx.x * 4 + wave;
    if (tile >= N_TILES) return;
    int node0 = tile * 16;
    int m = lane & 15, q = lane >> 4;
    bf16x8 A[4];
    const __hip_bfloat16* arow = h1rb + (size_t)(node0 + m) * F_HID + q * 8;
#pragma unroll
    for (int kt = 0; kt < 4; kt++)
        A[kt] = *(const bf16x8*)(arow + kt * 32);
#pragma unroll
    for (int c = 0; c < 3; c++) {
        f32x4 acc = {0.f, 0.f, 0.f, 0.f};
        const __hip_bfloat16* brow = w2t + (size_t)(c * 16 + m) * F_HID + q * 8;
#pragma unroll
        for (int kt = 0; kt < 4; kt++) {
            bf16x8 B = *(const bf16x8*)(brow + kt * 32);
            acc = __builtin_amdgcn_mfma_f32_16x16x32_bf16(A[kt], B, acc, 0, 0, 0);
        }
        int col = c * 16 + m;
        if (col < F_OUT) {
#pragma unroll
            for (int r = 0; r < 4; r++)
                h2b[(size_t)(node0 + q * 4 + r) * F_OUT + col] = __float2bfloat16(acc[r]);
        }
    }
}

// ---- 7. fused layer-2 aggregate + self-loop + bias + log_softmax. bf16 h2 gather.
__global__ void k_agg2f(const int* __restrict__ rowptr, const unsigned* __restrict__ srcw,
                        const float* __restrict__ dinv,
                        const unsigned short* __restrict__ h2b,
                        const float* __restrict__ b2, float* __restrict__ out) {
    int wave = threadIdx.x >> 6, lane = threadIdx.x & 63;
    int node = blockIdx.x * 4 + wave;
    float di = dinv[node];
    int beg = rowptr[node], end = rowptr[node + 1];
    int l = (lane < F_OUT) ? lane : 0;
    float acc = bf16u_to_f32(h2b[(size_t)node * F_OUT + l]) * di * di;
    int e = beg;
    for (; e + 3 < end; e += 4) {
        unsigned p0 = srcw[e], p1 = srcw[e + 1], p2 = srcw[e + 2], p3 = srcw[e + 3];
        float v0 = bf16u_to_f32(h2b[(size_t)(p0 & 0xFFFF) * F_OUT + l]);
        float v1 = bf16u_to_f32(h2b[(size_t)(p1 & 0xFFFF) * F_OUT + l]);
        float v2 = bf16u_to_f32(h2b[(size_t)(p2 & 0xFFFF) * F_OUT + l]);
        float v3 = bf16u_to_f32(h2b[(size_t)(p3 & 0xFFFF) * F_OUT + l]);
        acc += v0 * h16_to_f32(p0 >> 16) + v1 * h16_to_f32(p1 >> 16)
             + v2 * h16_to_f32(p2 >> 16) + v3 * h16_to_f32(p3 >> 16);
    }
    for (; e < end; e++) {
        unsigned p = srcw[e];
        acc += bf16u_to_f32(h2b[(size_t)(p & 0xFFFF) * F_OUT + l]) * h16_to_f32(p >> 16);
    }
    float v = (lane < F_OUT) ? acc + b2[lane] : -INFINITY;
    float m = v;
    for (int off = 32; off; off >>= 1) m = fmaxf(m, __shfl_xor(m, off));
    float ex = (lane < F_OUT) ? __expf(v - m) : 0.f;
    float ssum = ex;
    for (int off = 32; off; off >>= 1) ssum += __shfl_xor(ssum, off);
    float ls = __logf(ssum);
    if (lane < F_OUT)
        out[(size_t)node * F_OUT + lane] = v - m - ls;
}

extern "C" void kernel_launch(void* const* d_in, const int* in_sizes, int n_in,
                              void* d_out, int out_size, void* d_ws, size_t ws_size,
                              hipStream_t stream) {
    const float* x  = (const float*)d_in[0];
    const float* W1 = (const float*)d_in[1];
    const float* b1 = (const float*)d_in[2];
    const float* W2 = (const float*)d_in[3];
    const float* b2 = (const float*)d_in[4];
    const unsigned int* ew = (const unsigned int*)d_in[5];
    float* out = (float*)d_out;

    // workspace (~37 MB)
    char* ws = (char*)d_ws;
    int*   flag     = (int*)ws;   ws += 256;
    int*   gcnt     = (int*)ws;   ws += 512;
    float* dinv     = (float*)ws; ws += ((N_NODES * 4 + 255) / 256) * 256;
    int*   rowptr   = (int*)ws;   ws += (((N_NODES + 1) * 4 + 255) / 256) * 256;
    unsigned* gbin  = (unsigned*)ws; ws += (size_t)NBIN * GBIN_CAP * 4;   // 3.6 MB
    unsigned* srcw  = (unsigned*)ws; ws += (size_t)N_EDGES * 4;           // 3.2 MB
    __hip_bfloat16* w1t  = (__hip_bfloat16*)ws; ws += F_IN * F_HID * 2;
    __hip_bfloat16* w2t  = (__hip_bfloat16*)ws; ws += 48 * F_HID * 2;
    __hip_bfloat16* h1b  = (__hip_bfloat16*)ws; ws += (size_t)N_NODES * F_HID * 2;  // row-major
    __hip_bfloat16* h1rb = (__hip_bfloat16*)ws; ws += (size_t)N_NODES * F_HID * 2;  // row-major
    __hip_bfloat16* h2b  = (__hip_bfloat16*)ws; ws += (size_t)N_NODES * F_OUT * 2;

    k_init   <<<CVT_BLOCKS + 1, 256, 0, stream>>>(ew, W1, W2, w1t, w2t, flag, gcnt);
    k_bing1  <<<BIN_BLOCKS + G1_BLOCKS, 256, 0, stream>>>(ew, flag, gcnt, gbin, x, w1t, h1b);
    k_passB1 <<<NBIN, 256, 0, stream>>>(gcnt, gbin, rowptr, dinv);
    k_passB2 <<<NBIN, 256, 0, stream>>>(gcnt, gbin, rowptr, dinv, srcw);
    k_agg1f  <<<N_NODES / 4, 256, 0, stream>>>(rowptr, srcw, dinv, h1b, b1, h1rb);
    k_gemm2m <<<(N_TILES + 3) / 4, 256, 0, stream>>>(h1rb, w2t, h2b);
    k_agg2f  <<<N_NODES / 4, 256, 0, stream>>>(rowptr, srcw, dinv,
                                               (const unsigned short*)h2b, b2, out);
}

// Round 14
// 208.659 us; speedup vs baseline: 1.3267x; 1.0769x over previous
//
#include <hip/hip_runtime.h>
#include <hip/hip_bf16.h>

#define N_NODES 50000
#define N_EDGES 800000
#define F_IN    128
#define F_HID   128
#define F_OUT   40
#define N_TILES (N_NODES / 16)                // 3125 (exact)

#define NBIN      98                          // bins of 512 nodes (dst >> 9)
#define BIN_SHIFT 9
#define EPB       1024                        // edges per bin block
#define CAP       32                          // LDS slots per bin
#define GBIN_CAP  9216                        // global slots per bin

#define CVT_BLOCKS ((F_IN * F_HID + 48 * F_HID) / 256)   // 88
#define BIN_BLOCKS ((N_EDGES + EPB - 1) / EPB)           // 782
#define G1_BLOCKS  ((N_TILES + 3) / 4)                   // 782

typedef __attribute__((ext_vector_type(8))) short bf16x8;   // 8 bf16 = 4 VGPRs
typedef __attribute__((ext_vector_type(4))) float f32x4;

__device__ __forceinline__ float2 unpack_bf2(unsigned u) {
    float2 r;
    r.x = __uint_as_float(u << 16);
    r.y = __uint_as_float(u & 0xffff0000u);
    return r;
}
__device__ __forceinline__ unsigned pack_bf2(float x, float y) {
    union { unsigned u; __hip_bfloat16 h[2]; } cv;
    cv.h[0] = __float2bfloat16(x);
    cv.h[1] = __float2bfloat16(y);
    return cv.u;
}
__device__ __forceinline__ short bfraw(float v) {
    __hip_bfloat16 h = __float2bfloat16(v);
    return *(short*)&h;
}
__device__ __forceinline__ float bf16u_to_f32(unsigned short us) {
    return __uint_as_float(((unsigned)us) << 16);
}
__device__ __forceinline__ unsigned f32_to_h16(float v) {
    _Float16 h = (_Float16)v;
    return (unsigned)*(unsigned short*)&h;
}
__device__ __forceinline__ float h16_to_f32(unsigned bits) {
    unsigned short us = (unsigned short)bits;
    _Float16 h = *(_Float16*)&us;
    return (float)h;
}

__device__ __forceinline__ int ld_src(const unsigned int* w, int is64, int e) {
    return is64 ? (int)w[2 * e] : (int)w[e];
}
__device__ __forceinline__ int ld_dst(const unsigned int* w, int is64, int e) {
    return is64 ? (int)w[2 * (N_EDGES + e)] : (int)w[N_EDGES + e];
}

// ---- 1. init: blocks 0..87 convert W1/W2 to transposed bf16; block 88 sniffs
//         index width and zeroes gcnt.
__global__ void k_init(const unsigned int* __restrict__ ew,
                       const float* __restrict__ W1, const float* __restrict__ W2,
                       __hip_bfloat16* __restrict__ w1t, __hip_bfloat16* __restrict__ w2t,
                       int* __restrict__ flag, int* __restrict__ gcnt) {
    int b = blockIdx.x, t = threadIdx.x;
    if (b < CVT_BLOCKS) {
        int idx = b * 256 + t;
        if (idx < F_IN * F_HID) {
            int n = idx >> 7, k = idx & 127;
            w1t[idx] = __float2bfloat16(W1[k * F_HID + n]);
        } else {
            int j = idx - F_IN * F_HID;          // 0 .. 6143
            int n = j >> 7, k = j & 127;
            w2t[j] = __float2bfloat16(n < F_OUT ? W2[k * F_OUT + n] : 0.f);
        }
        return;
    }
    __shared__ int nz;
    if (t == 0) nz = 0;
    __syncthreads();
    int local = 0;
    for (int i = t; i < 4096; i += 256)
        if (ew[2 * i + 1] != 0u) local = 1;
    if (local) atomicOr(&nz, 1);
    if (t < NBIN) gcnt[t] = 0;
    __syncthreads();
    if (t == 0) flag[0] = (nz == 0) ? 1 : 0;     // 1 => int64 layout
}

// ---- 2. merged: blocks [0,782) bin edges; blocks [782,1564) MFMA gemm1 (row-major h1b).
__global__ void k_bing1(const unsigned int* __restrict__ ew, const int* __restrict__ flag,
                        int* __restrict__ gcnt, unsigned* __restrict__ gbin,
                        const float* __restrict__ x, const __hip_bfloat16* __restrict__ w1t,
                        __hip_bfloat16* __restrict__ h1b) {
    __shared__ unsigned buf[NBIN][CAP];        // 12.5 KB (unused by gemm blocks)
    __shared__ int cnt[NBIN];
    __shared__ int base[NBIN];
    int t = threadIdx.x;
    if (blockIdx.x < BIN_BLOCKS) {
        for (int i = t; i < NBIN; i += 256) cnt[i] = 0;
        __syncthreads();
        int is64 = flag[0];
        int e0 = blockIdx.x * EPB;
        int n = min(EPB, N_EDGES - e0);
        for (int i = t; i < n; i += 256) {
            int e = e0 + i;
            int s = ld_src(ew, is64, e), d = ld_dst(ew, is64, e);
            unsigned rec = (unsigned)s | ((unsigned)d << 16);
            int b = d >> BIN_SHIFT;
            int c = atomicAdd(&cnt[b], 1);
            if (c < CAP) buf[b][c] = rec;
            else {
                int g = atomicAdd(&gcnt[b], 1);
                gbin[(size_t)b * GBIN_CAP + g] = rec;
            }
        }
        __syncthreads();
        if (t < NBIN) {
            int m = min(cnt[t], CAP);
            base[t] = atomicAdd(&gcnt[t], m);
            cnt[t] = m;
        }
        __syncthreads();
        int wave = t >> 6, lane = t & 63;
        for (int b = wave; b < NBIN; b += 4) {
            int m = cnt[b], bs = base[b];
            for (int i = lane; i < m; i += 64)
                gbin[(size_t)b * GBIN_CAP + bs + i] = buf[b][i];
        }
        return;
    }
    // ---- gemm1 part
    int wave = t >> 6, lane = t & 63;
    int tile = (blockIdx.x - BIN_BLOCKS) * 4 + wave;
    if (tile >= N_TILES) return;
    int node0 = tile * 16;
    int m = lane & 15, q = lane >> 4;
    bf16x8 A[4];
    const float* arow = x + (size_t)(node0 + m) * F_IN + q * 8;
#pragma unroll
    for (int kt = 0; kt < 4; kt++) {
        float4 f0 = *(const float4*)(arow + kt * 32);
        float4 f1 = *(const float4*)(arow + kt * 32 + 4);
        bf16x8 a;
        a[0] = bfraw(f0.x); a[1] = bfraw(f0.y); a[2] = bfraw(f0.z); a[3] = bfraw(f0.w);
        a[4] = bfraw(f1.x); a[5] = bfraw(f1.y); a[6] = bfraw(f1.z); a[7] = bfraw(f1.w);
        A[kt] = a;
    }
#pragma unroll
    for (int c = 0; c < 8; c++) {
        f32x4 acc = {0.f, 0.f, 0.f, 0.f};
        const __hip_bfloat16* brow = w1t + (size_t)(c * 16 + m) * F_IN + q * 8;
#pragma unroll
        for (int kt = 0; kt < 4; kt++) {
            bf16x8 B = *(const bf16x8*)(brow + kt * 32);
            acc = __builtin_amdgcn_mfma_f32_16x16x32_bf16(A[kt], B, acc, 0, 0, 0);
        }
#pragma unroll
        for (int r = 0; r < 4; r++)
            h1b[(size_t)(node0 + q * 4 + r) * F_HID + c * 16 + m] = __float2bfloat16(acc[r]);
    }
}

// ---- 3. passB1: per-bin node histogram + scan -> rowptr, dinv (one block per bin)
__global__ void k_passB1(const int* __restrict__ gcnt, const unsigned* __restrict__ gbin,
                         int* __restrict__ rowptr, float* __restrict__ dinv) {
    __shared__ int c[512];
    __shared__ int s2[256];
    __shared__ int gall[NBIN];
    __shared__ int bbase;
    int t = threadIdx.x;
    int b = blockIdx.x;
    c[t] = 0; c[t + 256] = 0;
    if (t < NBIN) gall[t] = gcnt[t];
    __syncthreads();
    if (t == 0) {
        int s = 0;
        for (int i = 0; i < b; i++) s += gall[i];
        bbase = s;
    }
    int n = gall[b];
    const unsigned* rec = gbin + (size_t)b * GBIN_CAP;
    int base512 = b << BIN_SHIFT;
    for (int i = t; i < n; i += 256)
        atomicAdd(&c[(int)(rec[i] >> 16) - base512], 1);
    __syncthreads();
    int a0 = c[2 * t], a1 = c[2 * t + 1];
    s2[t] = a0 + a1;
    __syncthreads();
    for (int off = 1; off < 256; off <<= 1) {
        int u = (t >= off) ? s2[t - off] : 0;
        __syncthreads();
        s2[t] += u;
        __syncthreads();
    }
    int ebase = bbase + s2[t] - a0 - a1;
    int i0 = base512 + 2 * t, i1 = i0 + 1;
    if (i0 < N_NODES) { rowptr[i0] = ebase;      dinv[i0] = rsqrtf((float)a0 + 1.f); }
    if (i1 < N_NODES) { rowptr[i1] = ebase + a0; dinv[i1] = rsqrtf((float)a1 + 1.f); }
    if (b == 0 && t == 0) rowptr[N_NODES] = N_EDGES;
}

// ---- 4. passB2: scatter bin records to final CSR slots (block-local dense window)
__global__ void k_passB2(const int* __restrict__ gcnt, const unsigned* __restrict__ gbin,
                         const int* __restrict__ rowptr, const float* __restrict__ dinv,
                         unsigned* __restrict__ srcw) {
    __shared__ int pos[512];
    __shared__ float dloc[512];
    int t = threadIdx.x;
    int b = blockIdx.x;
    int base512 = b << BIN_SHIFT;
#pragma unroll
    for (int k = 0; k < 2; k++) {
        int j = t + k * 256;
        int i = base512 + j;
        pos[j]  = (i < N_NODES) ? rowptr[i] : 0;
        dloc[j] = (i < N_NODES) ? dinv[i] : 0.f;
    }
    __syncthreads();
    int n = gcnt[b];
    const unsigned* rec = gbin + (size_t)b * GBIN_CAP;
    for (int i = t; i < n; i += 256) {
        unsigned r = rec[i];
        int s  = (int)(r & 0xFFFFu);
        int dl = (int)(r >> 16) - base512;
        int slot = atomicAdd(&pos[dl], 1);
        float norm = dinv[s] * dloc[dl];
        srcw[slot] = (unsigned)s | (f32_to_h16(norm) << 16);
    }
}

// ---- 5. fused layer-1 aggregate + self-loop + bias + relu.
//         Edge records loaded via SCALAR path (readfirstlane'd uniform indices
//         -> s_load through constant cache), 8 records per batch; row-gathers
//         issue back-to-back with MLP=8.
__global__ void k_agg1f(const int* __restrict__ rowptr, const unsigned* __restrict__ srcw,
                        const float* __restrict__ dinv, const __hip_bfloat16* __restrict__ h1b,
                        const float* __restrict__ b1, __hip_bfloat16* __restrict__ h1rb) {
    int wave = threadIdx.x >> 6, lane = threadIdx.x & 63;
    int node = blockIdx.x * 4 + wave;
    float di = dinv[node];
    int beg = __builtin_amdgcn_readfirstlane(rowptr[node]);
    int end = __builtin_amdgcn_readfirstlane(rowptr[node + 1]);
    const unsigned* h1u = (const unsigned*)h1b;
    float2 acc = unpack_bf2(h1u[(size_t)node * 64 + lane]);
    float w0 = di * di;
    acc.x *= w0; acc.y *= w0;
    int e = beg;
    for (; e + 7 < end; e += 8) {
        unsigned p[8];
#pragma unroll
        for (int j = 0; j < 8; j++) p[j] = srcw[e + j];     // uniform addr -> s_load
        unsigned u[8];
#pragma unroll
        for (int j = 0; j < 8; j++)
            u[j] = h1u[(size_t)(p[j] & 0xFFFFu) * 64 + lane];
#pragma unroll
        for (int j = 0; j < 8; j++) {
            float w = h16_to_f32(p[j] >> 16);
            float2 v = unpack_bf2(u[j]);
            acc.x += v.x * w;
            acc.y += v.y * w;
        }
    }
    for (; e < end; e++) {
        unsigned p = srcw[e];
        float w = h16_to_f32(p >> 16);
        float2 v = unpack_bf2(h1u[(size_t)(p & 0xFFFFu) * 64 + lane]);
        acc.x += v.x * w;
        acc.y += v.y * w;
    }
    float2 bb = ((const float2*)b1)[lane];
    acc.x = fmaxf(acc.x + bb.x, 0.f);
    acc.y = fmaxf(acc.y + bb.y, 0.f);
    ((unsigned*)h1rb)[(size_t)node * 64 + lane] = pack_bf2(acc.x, acc.y);
}

// ---- 6. h2 = h1r @ W2 via MFMA (N padded 40->48). h2 out BF16.
__global__ void k_gemm2m(const __hip_bfloat16* __restrict__ h1rb,
                         const __hip_bfloat16* __restrict__ w2t,
                         __hip_bfloat16* __restrict__ h2b) {
    int wave = threadIdx.x >> 6, lane = threadIdx.x & 63;
    int tile = blockIdx.x * 4 + wave;
    if (tile >= N_TILES) return;
    int node0 = tile * 16;
    int m = lane & 15, q = lane >> 4;
    bf16x8 A[4];
    const __hip_bfloat16* arow = h1rb + (size_t)(node0 + m) * F_HID + q * 8;
#pragma unroll
    for (int kt = 0; kt < 4; kt++)
        A[kt] = *(const bf16x8*)(arow + kt * 32);
#pragma unroll
    for (int c = 0; c < 3; c++) {
        f32x4 acc = {0.f, 0.f, 0.f, 0.f};
        const __hip_bfloat16* brow = w2t + (size_t)(c * 16 + m) * F_HID + q * 8;
#pragma unroll
        for (int kt = 0; kt < 4; kt++) {
            bf16x8 B = *(const bf16x8*)(brow + kt * 32);
            acc = __builtin_amdgcn_mfma_f32_16x16x32_bf16(A[kt], B, acc, 0, 0, 0);
        }
        int col = c * 16 + m;
        if (col < F_OUT) {
#pragma unroll
            for (int r = 0; r < 4; r++)
                h2b[(size_t)(node0 + q * 4 + r) * F_OUT + col] = __float2bfloat16(acc[r]);
        }
    }
}

// ---- 7. fused layer-2 aggregate + self-loop + bias + log_softmax.
//         Same scalar edge-record path; bf16 h2 gather.
__global__ void k_agg2f(const int* __restrict__ rowptr, const unsigned* __restrict__ srcw,
                        const float* __restrict__ dinv,
                        const unsigned short* __restrict__ h2b,
                        const float* __restrict__ b2, float* __restrict__ out) {
    int wave = threadIdx.x >> 6, lane = threadIdx.x & 63;
    int node = blockIdx.x * 4 + wave;
    float di = dinv[node];
    int beg = __builtin_amdgcn_readfirstlane(rowptr[node]);
    int end = __builtin_amdgcn_readfirstlane(rowptr[node + 1]);
    int l = (lane < F_OUT) ? lane : 0;
    float acc = bf16u_to_f32(h2b[(size_t)node * F_OUT + l]) * di * di;
    int e = beg;
    for (; e + 7 < end; e += 8) {
        unsigned p[8];
#pragma unroll
        for (int j = 0; j < 8; j++) p[j] = srcw[e + j];     // uniform addr -> s_load
        float v[8];
#pragma unroll
        for (int j = 0; j < 8; j++)
            v[j] = bf16u_to_f32(h2b[(size_t)(p[j] & 0xFFFFu) * F_OUT + l]);
#pragma unroll
        for (int j = 0; j < 8; j++)
            acc += v[j] * h16_to_f32(p[j] >> 16);
    }
    for (; e < end; e++) {
        unsigned p = srcw[e];
        acc += bf16u_to_f32(h2b[(size_t)(p & 0xFFFFu) * F_OUT + l]) * h16_to_f32(p >> 16);
    }
    float v = (lane < F_OUT) ? acc + b2[lane] : -INFINITY;
    float m = v;
    for (int off = 32; off; off >>= 1) m = fmaxf(m, __shfl_xor(m, off));
    float ex = (lane < F_OUT) ? __expf(v - m) : 0.f;
    float ssum = ex;
    for (int off = 32; off; off >>= 1) ssum += __shfl_xor(ssum, off);
    float ls = __logf(ssum);
    if (lane < F_OUT)
        out[(size_t)node * F_OUT + lane] = v - m - ls;
}

extern "C" void kernel_launch(void* const* d_in, const int* in_sizes, int n_in,
                              void* d_out, int out_size, void* d_ws, size_t ws_size,
                              hipStream_t stream) {
    const float* x  = (const float*)d_in[0];
    const float* W1 = (const float*)d_in[1];
    const float* b1 = (const float*)d_in[2];
    const float* W2 = (const float*)d_in[3];
    const float* b2 = (const float*)d_in[4];
    const unsigned int* ew = (const unsigned int*)d_in[5];
    float* out = (float*)d_out;

    // workspace (~37 MB)
    char* ws = (char*)d_ws;
    int*   flag     = (int*)ws;   ws += 256;
    int*   gcnt     = (int*)ws;   ws += 512;
    float* dinv     = (float*)ws; ws += ((N_NODES * 4 + 255) / 256) * 256;
    int*   rowptr   = (int*)ws;   ws += (((N_NODES + 1) * 4 + 255) / 256) * 256;
    unsigned* gbin  = (unsigned*)ws; ws += (size_t)NBIN * GBIN_CAP * 4;   // 3.6 MB
    unsigned* srcw  = (unsigned*)ws; ws += (size_t)N_EDGES * 4;           // 3.2 MB
    __hip_bfloat16* w1t  = (__hip_bfloat16*)ws; ws += F_IN * F_HID * 2;
    __hip_bfloat16* w2t  = (__hip_bfloat16*)ws; ws += 48 * F_HID * 2;
    __hip_bfloat16* h1b  = (__hip_bfloat16*)ws; ws += (size_t)N_NODES * F_HID * 2;  // row-major
    __hip_bfloat16* h1rb = (__hip_bfloat16*)ws; ws += (size_t)N_NODES * F_HID * 2;  // row-major
    __hip_bfloat16* h2b  = (__hip_bfloat16*)ws; ws += (size_t)N_NODES * F_OUT * 2;

    k_init   <<<CVT_BLOCKS + 1, 256, 0, stream>>>(ew, W1, W2, w1t, w2t, flag, gcnt);
    k_bing1  <<<BIN_BLOCKS + G1_BLOCKS, 256, 0, stream>>>(ew, flag, gcnt, gbin, x, w1t, h1b);
    k_passB1 <<<NBIN, 256, 0, stream>>>(gcnt, gbin, rowptr, dinv);
    k_passB2 <<<NBIN, 256, 0, stream>>>(gcnt, gbin, rowptr, dinv, srcw);
    k_agg1f  <<<N_NODES / 4, 256, 0, stream>>>(rowptr, srcw, dinv, h1b, b1, h1rb);
    k_gemm2m <<<(N_TILES + 3) / 4, 256, 0, stream>>>(h1rb, w2t, h2b);
    k_agg2f  <<<N_NODES / 4, 256, 0, stream>>>(rowptr, srcw, dinv,
                                               (const unsigned short*)h2b, b2, out);
}